// Round 4
// baseline (271.056 us; speedup 1.0000x reference)
//
#include <hip/hip_runtime.h>
#include <hip/hip_bf16.h>

// WeightedLoss round 23: fix the supertile's two memory anomalies.
// r22 falsified the spill theory (VGPR 128 both bounds, identical counters:
// acc lives in 128 AGPRs, 128+128=256 fits 2 waves/SIMD, no spill). Real
// pathologies: (1) FETCH 168MB on a 6MB dataset -> L2 thrash from cohort
// shape (each XCD's 32 concurrent blocks needed ~7MB of panels in a 4MB L2);
// (2) WRITE 270MB = 137 + 133(logical stores AGAIN) -> every NT-store line
// written twice; nt-flag streaming is the suspect. Fixes: (a) 8x8-square
// band-major tile enumeration so bid%8 round-robin gives each XCD 8 A-rows
// x ~4 B-cols = 2.3MB < 4MB L2; (b) plain (non-NT) sim/eud stores.
// Counters attribute independently: FETCH<-mapping, WRITE<-store flag.
// Fallback pre-committed: any anomaly persists -> revert to r19 stats.
// ws: [0] Obp packed 4 MB | [4194304] Lnp packed 2 MB | [6291456] sq
//     [6324224] pos_sums | [6356992] neg_sums | [6389760] stats u32[3]
//     [6389824] simT fp16 2080x16384 (68.2 MB) | [74547264] eudT (68.2 MB)

#define B_N 8192
#define TILE 128
#define NTRI 2080
#define NSUP 528
#define WS_NEEDED 142704704ull

typedef __attribute__((ext_vector_type(8))) short bf16x8;
typedef __attribute__((ext_vector_type(4))) float f32x4;
typedef __attribute__((ext_vector_type(2))) _Float16 f16x2;
typedef __attribute__((ext_vector_type(4))) unsigned u32x4;

typedef const __attribute__((address_space(1))) void g_void;
typedef __attribute__((address_space(3))) void l_void;

__device__ __forceinline__ unsigned fenc(float f) {
    unsigned u = __float_as_uint(f);
    return (u & 0x80000000u) ? ~u : (u | 0x80000000u);
}
__device__ __forceinline__ float fdec(unsigned k) {
    unsigned u = (k & 0x80000000u) ? (k ^ 0x80000000u) : ~k;
    return __uint_as_float(u);
}
__device__ __forceinline__ unsigned pack2(float a, float b) {
    f16x2 p; p[0] = (_Float16)a; p[1] = (_Float16)b;
    return *(unsigned*)&p;
}

// Supertile decode: 4 diagonal 16x16-tri supertiles (136 tiles, b<544),
// then 6 off-diagonal 16x16 supertiles (256 tiles each). bi<=bj always.
__device__ __forceinline__ void tile_decode(int b, int& bi, int& bj) {
    int si, sj, ti, tj;
    if (b < 544) {
        int sb = b / 136, w = b - sb * 136;
        int i = 0;
        while (w >= 16 - i) { w -= 16 - i; i++; }
        si = sb; sj = sb; ti = i; tj = i + w;
    } else {
        int q = (b - 544) >> 8, w = (b - 544) & 255;
        int i = 0;
        while (q >= 3 - i) { q -= 3 - i; i++; }
        si = i; sj = i + 1 + q;
        ti = w >> 4; tj = w & 15;
    }
    bi = si * 16 + ti; bj = sj * 16 + tj;
}

// Closed-form inverse of tile_decode (bi<=bj, 64x64 tile space).
__device__ __forceinline__ int tile_encode(int bi, int bj) {
    int si = bi >> 4, sj = bj >> 4, ti = bi & 15, tj = bj & 15;
    if (si == sj) return si * 136 + ti * 16 - (ti * (ti - 1)) / 2 + (tj - ti);
    int off = 3 * si - (si * (si - 1)) / 2 + (sj - si - 1);
    return 544 + off * 256 + ti * 16 + tj;
}

// Cohort-shaped supertile enumeration (32x32 upper triangle, 528 cells).
// Bands of 8 BI-rows; within a band: the 8x8 diagonal corner triangle,
// then full 8x8 BJ-squares, ROW-MAJOR within each square. With hardware
// bid%8 -> XCD round-robin, each XCD gets one BJ-column per square:
// concurrent working set per XCD = 8 A-rows + ~4 B-cols = ~12 panels
// = 2.3MB < 4MB L2.
__device__ __forceinline__ void super_decode(int bid, int& BI, int& BJ) {
    int b = (bid >= 492) ? 3 : (bid >= 392) ? 2 : (bid >= 228) ? 1 : 0;
    int w = bid - ((b == 3) ? 492 : (b == 2) ? 392 : (b == 1) ? 228 : 0);
    int bi_l, bj_l, g;
    if (w < 36) {
        int i = 0;
        while (w >= 8 - i) { w -= 8 - i; i++; }
        bi_l = i; bj_l = i + w; g = b;
    } else {
        w -= 36;
        g = b + 1 + (w >> 6);
        int r = w & 63;
        bi_l = r >> 3; bj_l = r & 7;
    }
    BI = b * 8 + bi_l; BJ = g * 8 + bj_l;
}

// ---------------------------------------------------------------- prep ----
__global__ __launch_bounds__(256) void prep_kernel(
    const float* __restrict__ outputs, const float* __restrict__ labels,
    __hip_bfloat16* __restrict__ Obp, __hip_bfloat16* __restrict__ Lnp,
    float* __restrict__ sq, float* __restrict__ pos_sums,
    float* __restrict__ neg_sums, unsigned* __restrict__ stats) {
    int g = blockIdx.x, tid = threadIdx.x;
    int rl = tid >> 4, c = tid & 15;
    int row = g * 16 + rl;
    __shared__ __align__(16) short tO[16][264];
    __shared__ __align__(16) short tL[16][136];

    float s = 0.f;
    #pragma unroll
    for (int k = 0; k < 4; k++) {
        f32x4 v = *(const f32x4*)&outputs[(size_t)row * 256 + c * 16 + k * 4];
        s += v[0]*v[0] + v[1]*v[1] + v[2]*v[2] + v[3]*v[3];
        __hip_bfloat16 b4[4];
        #pragma unroll
        for (int i = 0; i < 4; i++) b4[i] = __float2bfloat16(v[i]);
        *(uint2*)&tO[rl][c * 16 + k * 4] = *(uint2*)b4;
    }
    #pragma unroll
    for (int m = 1; m < 16; m <<= 1) s += __shfl_xor(s, m);
    if (c == 0) sq[row] = s;

    float ls = 0.f;
    f32x4 u0 = *(const f32x4*)&labels[(size_t)row * 128 + c * 8];
    f32x4 u1 = *(const f32x4*)&labels[(size_t)row * 128 + c * 8 + 4];
    ls += u0[0]*u0[0] + u0[1]*u0[1] + u0[2]*u0[2] + u0[3]*u0[3];
    ls += u1[0]*u1[0] + u1[1]*u1[1] + u1[2]*u1[2] + u1[3]*u1[3];
    #pragma unroll
    for (int m = 1; m < 16; m <<= 1) ls += __shfl_xor(ls, m);
    float inv = 1.f / (sqrtf(ls) + 1e-12f);
    {
        __hip_bfloat16 b4[4];
        #pragma unroll
        for (int i = 0; i < 4; i++) b4[i] = __float2bfloat16(u0[i] * inv);
        *(uint2*)&tL[rl][c * 8] = *(uint2*)b4;
        #pragma unroll
        for (int i = 0; i < 4; i++) b4[i] = __float2bfloat16(u1[i] * inv);
        *(uint2*)&tL[rl][c * 8 + 4] = *(uint2*)b4;
    }
    if (tid < 16) { pos_sums[g * 16 + tid] = 0.f; neg_sums[g * 16 + tid] = 0.f; }
    if (g == 0 && tid == 0) {
        stats[0] = 0xFFFFFFFFu; stats[1] = 0u; stats[2] = 0u;
    }
    __syncthreads();

    #pragma unroll
    for (int q = 0; q < 2; q++) {
        int sl = tid * 2 + q;
        int o = sl >> 4, rr = sl & 15;
        uint4 d = *(uint4*)&tO[rr][o * 8];
        *(uint4*)&Obp[(size_t)g * 4096 + (size_t)sl * 8] = d;
    }
    {
        int o = tid >> 4, rr = tid & 15;
        uint4 d = *(uint4*)&tL[rr][o * 8];
        *(uint4*)&Lnp[(size_t)g * 2048 + (size_t)tid * 8] = d;
    }
}

// ------------------------------------------------- staged slice gram ----
// (256-thread helpers kept for the loss_recompute fallback)
template<int KD8>
__device__ __forceinline__ void stage_slice(
    const short* __restrict__ P, int g0, int o0, short* L, int tid) {
    #pragma unroll
    for (int p = 0; p < 4; p++) {
        int u = p * 256 + tid;
        int gl = u >> 7, off = u & 127;
        size_t gu = ((size_t)(g0 + gl) * KD8 + o0) * 16 + off;
        __builtin_amdgcn_global_load_lds((g_void*)(P + gu * 8),
                                         (l_void*)(L + (size_t)u * 8), 16, 0, 0);
    }
}

__device__ __forceinline__ void mfma_slice(
    const short* As, const short* Bs, int wm4, int wn4,
    int l15, int quad, f32x4 (&acc)[4][4]) {
    #pragma unroll
    for (int kc = 0; kc < 2; kc++) {
        bf16x8 a[4], b[4];
        #pragma unroll
        for (int mi = 0; mi < 4; mi++)
            a[mi] = *(const bf16x8*)&As[((wm4 + mi) * 128
                                         + (kc * 4 + quad) * 16 + l15) * 8];
        #pragma unroll
        for (int ni = 0; ni < 4; ni++)
            b[ni] = *(const bf16x8*)&Bs[((wn4 + ni) * 128
                                         + (kc * 4 + quad) * 16 + l15) * 8];
        #pragma unroll
        for (int mi = 0; mi < 4; mi++)
            #pragma unroll
            for (int ni = 0; ni < 4; ni++)
                acc[mi][ni] = __builtin_amdgcn_mfma_f32_16x16x32_bf16(
                    a[mi], b[ni], acc[mi][ni], 0, 0, 0);
    }
}

__device__ __forceinline__ void zero_acc(f32x4 (&acc)[4][4]) {
    #pragma unroll
    for (int mi = 0; mi < 4; mi++)
        #pragma unroll
        for (int ni = 0; ni < 4; ni++) {
            f32x4 z = {0.f, 0.f, 0.f, 0.f};
            acc[mi][ni] = z;
        }
}

template<int KD8, int NS>
__device__ __forceinline__ void gram_staged(
    const short* __restrict__ P, int gA0, int gB0,
    short* As, short* Bs, int tid, int wm4, int wn4,
    int l15, int quad, f32x4 (&acc)[4][4]) {
    #pragma unroll
    for (int s = 0; s < NS; s++) {
        __syncthreads();
        stage_slice<KD8>(P, gA0, s * 8, As, tid);
        stage_slice<KD8>(P, gB0, s * 8, Bs, tid);
        __syncthreads();
        mfma_slice(As, Bs, wm4, wn4, l15, quad, acc);
    }
}

// ----------------------------------------------- 512-thread supertile ----
__device__ __forceinline__ void stage512(const short* __restrict__ P, int g0,
                                         int kd8, int o0, short* L, int tid) {
    #pragma unroll
    for (int p = 0; p < 4; p++) {
        int u = p * 512 + tid;
        int gl = u >> 7, off = u & 127;
        size_t gu = ((size_t)(g0 + gl) * kd8 + o0) * 16 + off;
        __builtin_amdgcn_global_load_lds((g_void*)(P + gu * 8),
                                         (l_void*)(L + (size_t)u * 8), 16, 0, 0);
    }
}

__device__ __forceinline__ void mfma64(const short* As, const short* Bs,
                                       int wr8, int wc4, int l15, int quad,
                                       f32x4 (&acc)[8][4]) {
    #pragma unroll
    for (int kc = 0; kc < 2; kc++) {
        bf16x8 a[8], b[4];
        #pragma unroll
        for (int am = 0; am < 8; am++)
            a[am] = *(const bf16x8*)&As[((wr8 + am) * 128
                                         + (kc * 4 + quad) * 16 + l15) * 8];
        #pragma unroll
        for (int bn = 0; bn < 4; bn++)
            b[bn] = *(const bf16x8*)&Bs[((wc4 + bn) * 128
                                         + (kc * 4 + quad) * 16 + l15) * 8];
        #pragma unroll
        for (int am = 0; am < 8; am++)
            #pragma unroll
            for (int bn = 0; bn < 4; bn++)
                acc[am][bn] = __builtin_amdgcn_mfma_f32_16x16x32_bf16(
                    a[am], b[bn], acc[am][bn], 0, 0, 0);
    }
}

__device__ __forceinline__ void zero_acc8(f32x4 (&acc)[8][4]) {
    #pragma unroll
    for (int mi = 0; mi < 8; mi++)
        #pragma unroll
        for (int ni = 0; ni < 4; ni++) {
            f32x4 z = {0.f, 0.f, 0.f, 0.f};
            acc[mi][ni] = z;
        }
}

#define VMCNT(n) asm volatile("s_waitcnt vmcnt(" #n ")" ::: "memory")
#define BAR() __builtin_amdgcn_s_barrier()

// ---------------------------------------------------------------- stats ----
// 256^2 supertile per block, 8 waves (2 row x 4 col of 128x64 each),
// double-buffered 128KB LDS. Counted-vmcnt pipeline as r21/r22 (verified).
// r23: cohort-shaped super_decode (L2-resident panels per XCD) and PLAIN
// sim/eud stores (A/B vs nt: tests the 2x write amplification).
__global__ __launch_bounds__(512, 1) void stats_kernel(
    const short* __restrict__ Lnp, const short* __restrict__ Obp,
    const float* __restrict__ sq, unsigned* __restrict__ stats,
    unsigned* __restrict__ simT, unsigned* __restrict__ eudT, int store) {
    int BI, BJ;
    super_decode(blockIdx.x, BI, BJ);

    int tid = threadIdx.x, lane = tid & 63, wid = tid >> 6;
    int wr = wid >> 2, wc = wid & 3;
    int l15 = lane & 15, quad = lane >> 4;
    int wr8 = wr * 8, wc4 = wc * 4;
    int wcH = wc >> 1, wcL = wc & 1;

    __shared__ __align__(16) short As[2][16384];
    __shared__ __align__(16) short Bs[2][16384];
    __shared__ float red[3][8];

    int gA = BI * 16, gB = BJ * 16;
    bool dostore = store && !(BI == BJ && wr == 1 && wcH == 0);
    int b128 = tile_encode(BI * 2 + wr, BJ * 2 + wcH);
    size_t blkbase = (size_t)b128 * 8192;

    float lmin = 1e30f, lmax = -1e30f, dmax = 0.f;
    f32x4 acc[8][4];

    // ---- labels gram (K=128 -> slices L0, L1) ----
    zero_acc8(acc);
    stage512(Lnp, gA, 16, 0, &As[0][0], tid);    // L0  [8]
    stage512(Lnp, gB, 16, 0, &Bs[0][0], tid);
    stage512(Lnp, gA, 16, 8, &As[1][0], tid);    // L1  [16]
    stage512(Lnp, gB, 16, 8, &Bs[1][0], tid);
    VMCNT(8); BAR();                             // L0 landed everywhere
    mfma64(&As[0][0], &Bs[0][0], wr8, wc4, l15, quad, acc);
    BAR();                                       // buf0 free
    stage512(Obp, gA, 32, 0, &As[0][0], tid);    // O0  [L1:8 + O0:8]
    stage512(Obp, gB, 32, 0, &Bs[0][0], tid);
    VMCNT(8); BAR();                             // L1 landed (oldest 8)
    mfma64(&As[1][0], &Bs[1][0], wr8, wc4, l15, quad, acc);
    BAR();                                       // buf1 free
    stage512(Obp, gA, 32, 8, &As[1][0], tid);    // O1  [O0:8 + O1:8]
    stage512(Obp, gB, 32, 8, &Bs[1][0], tid);

    // ---- sim epilogue: pack + min/max + stores (fills O0/O1 latency) ----
    #pragma unroll
    for (int am = 0; am < 8; am++) {
        int tid128 = (((am >> 2) << 1) | wcL) * 64 + lane;
        #pragma unroll
        for (int bh = 0; bh < 2; bh++) {
            u32x4 v;
            #pragma unroll
            for (int b2 = 0; b2 < 2; b2++) {
                int bn = bh * 2 + b2;
                #pragma unroll
                for (int h = 0; h < 2; h++) {
                    float s0 = acc[am][bn][2 * h], s1 = acc[am][bn][2 * h + 1];
                    lmin = fminf(lmin, fminf(s0, s1));
                    lmax = fmaxf(lmax, fmaxf(s0, s1));
                    v[b2 * 2 + h] = pack2(s0, s1);
                }
            }
            if (dostore)
                *(u32x4*)(simT + blkbase
                    + ((am & 3) * 2 + bh) * 1024 + tid128 * 4) = v;
        }
    }                                            // [O0:8 + O1:8 + st:16]

    // ---- outputs gram (K=256 -> O0..O3, pipelined) ----
    zero_acc8(acc);
    VMCNT(24); BAR();                            // O0 landed (<= O1+stores)
    mfma64(&As[0][0], &Bs[0][0], wr8, wc4, l15, quad, acc);
    BAR();                                       // buf0 free
    stage512(Obp, gA, 32, 16, &As[0][0], tid);   // O2
    stage512(Obp, gB, 32, 16, &Bs[0][0], tid);
    VMCNT(8); BAR();                             // O1 landed (older sts drained)
    mfma64(&As[1][0], &Bs[1][0], wr8, wc4, l15, quad, acc);
    BAR();                                       // buf1 free
    stage512(Obp, gA, 32, 24, &As[1][0], tid);   // O3
    stage512(Obp, gB, 32, 24, &Bs[1][0], tid);
    VMCNT(8); BAR();                             // O2 landed
    // sq loads (12 VMEM, younger than O3) fill O3 latency
    f32x4 sqi[8]; float sqj[4];
    {
        int rqa = BI * 256 + wr * 128 + quad * 4;
        int cqa = BJ * 256 + wc * 64 + l15;
        #pragma unroll
        for (int am = 0; am < 8; am++)
            sqi[am] = *(const f32x4*)&sq[rqa + am * 16];
        #pragma unroll
        for (int bn = 0; bn < 4; bn++)
            sqj[bn] = sq[cqa + bn * 16];
    }
    mfma64(&As[0][0], &Bs[0][0], wr8, wc4, l15, quad, acc);
    VMCNT(12); BAR();                            // O3 landed (sq younger)
    mfma64(&As[1][0], &Bs[1][0], wr8, wc4, l15, quad, acc);

    // ---- eud epilogue ----
    #pragma unroll
    for (int am = 0; am < 8; am++) {
        int tid128 = (((am >> 2) << 1) | wcL) * 64 + lane;
        f32x4 si = sqi[am];
        #pragma unroll
        for (int bh = 0; bh < 2; bh++) {
            u32x4 v;
            #pragma unroll
            for (int b2 = 0; b2 < 2; b2++) {
                int bn = bh * 2 + b2;
                float sj = sqj[bn];
                #pragma unroll
                for (int h = 0; h < 2; h++) {
                    float d20 = fmaxf(si[2*h]   + sj - 2.f * acc[am][bn][2*h],   0.f);
                    float d21 = fmaxf(si[2*h+1] + sj - 2.f * acc[am][bn][2*h+1], 0.f);
                    dmax = fmaxf(dmax, fmaxf(d20, d21));
                    float e0 = (d20 > 0.f) ? sqrtf(d20) : 0.f;
                    float e1 = (d21 > 0.f) ? sqrtf(d21) : 0.f;
                    v[b2 * 2 + h] = pack2(e0, e1);
                }
            }
            if (dostore)
                *(u32x4*)(eudT + blkbase
                    + ((am & 3) * 2 + bh) * 1024 + tid128 * 4) = v;
        }
    }

    // ---- reductions ----
    #pragma unroll
    for (int m = 1; m < 64; m <<= 1) {
        lmin = fminf(lmin, __shfl_xor(lmin, m));
        lmax = fmaxf(lmax, __shfl_xor(lmax, m));
        dmax = fmaxf(dmax, __shfl_xor(dmax, m));
    }
    if (lane == 0) { red[0][wid] = lmin; red[1][wid] = lmax; red[2][wid] = dmax; }
    __syncthreads();
    if (tid == 0) {
        lmin = red[0][0]; lmax = red[1][0]; dmax = red[2][0];
        #pragma unroll
        for (int w = 1; w < 8; w++) {
            lmin = fminf(lmin, red[0][w]);
            lmax = fmaxf(lmax, red[1][w]);
            dmax = fmaxf(dmax, red[2][w]);
        }
        atomicMin(&stats[0], fenc(lmin));
        atomicMax(&stats[1], fenc(lmax));
        atomicMax(&stats[2], fenc(dmax));
    }
}

// ----------------------------------------------------------- loss stream ----
// Pure streaming epilogue (r7-verified): coalesced NT dwordx4 reads,
// exp terms, row+col sums, one atomic per row per block.
__global__ __launch_bounds__(256) void loss_stream_kernel(
    const unsigned* __restrict__ simT, const unsigned* __restrict__ eudT,
    const unsigned* __restrict__ stats,
    float* __restrict__ pos_sums, float* __restrict__ neg_sums) {
    int bi, bj;
    tile_decode(blockIdx.x, bi, bj);
    int tid = threadIdx.x, lane = tid & 63, wid = tid >> 6;
    int wm = (wid >> 1) * 64, wn = (wid & 1) * 64;
    int l15 = lane & 15, quad = lane >> 4;
    size_t tB = (size_t)blockIdx.x * 8192 + (size_t)tid * 4;

    float smin = fdec(stats[0]);
    float smax = fdec(stats[1]);
    float d2max = fdec(stats[2]);
    float invr = 1.f / (smax - smin);
    float invem = rsqrtf(d2max);

    __shared__ float rP[TILE][2], rN[TILE][2];
    __shared__ float cP[TILE][2], cN[TILE][2];
    float cpsum[4] = {0.f, 0.f, 0.f, 0.f};
    float cnsum[4] = {0.f, 0.f, 0.f, 0.f};

    #pragma unroll
    for (int mi = 0; mi < 4; mi++) {
        u32x4 s0 = __builtin_nontemporal_load((const u32x4*)(simT + tB + (mi * 2 + 0) * 1024));
        u32x4 s1 = __builtin_nontemporal_load((const u32x4*)(simT + tB + (mi * 2 + 1) * 1024));
        u32x4 e0 = __builtin_nontemporal_load((const u32x4*)(eudT + tB + (mi * 2 + 0) * 1024));
        u32x4 e1 = __builtin_nontemporal_load((const u32x4*)(eudT + tB + (mi * 2 + 1) * 1024));
        float ps[4] = {0.f, 0.f, 0.f, 0.f};
        float ns[4] = {0.f, 0.f, 0.f, 0.f};
        #pragma unroll
        for (int j = 0; j < 8; j++) {
            unsigned sv = (j < 4) ? s0[j] : s1[j - 4];
            unsigned ev = (j < 4) ? e0[j] : e1[j - 4];
            int ni = j >> 1, h = j & 1;
            f16x2 spair = *(f16x2*)&sv;
            f16x2 epair = *(f16x2*)&ev;
            #pragma unroll
            for (int e = 0; e < 2; e++) {
                float sn = ((float)spair[e] - smin) * invr;
                float dist = (float)epair[e] * invem + sn;
                bool pos = sn > 0.5f;   // TAU
                float pv = pos ? __expf(dist) : 0.f;
                float nv = pos ? 0.f : __expf(1.0f - dist);  // MAG = 1
                ps[2 * h + e] += pv;  ns[2 * h + e] += nv;
                cpsum[ni] += pv;  cnsum[ni] += nv;
            }
        }
        #pragma unroll
        for (int r = 0; r < 4; r++) {
            #pragma unroll
            for (int m = 1; m < 16; m <<= 1) {
                ps[r] += __shfl_xor(ps[r], m);
                ns[r] += __shfl_xor(ns[r], m);
            }
            if (l15 == 0) {
                int rr = wm + mi * 16 + quad * 4 + r;
                rP[rr][wid & 1] = ps[r];
                rN[rr][wid & 1] = ns[r];
            }
        }
    }
    #pragma unroll
    for (int ni = 0; ni < 4; ni++) {
        #pragma unroll
        for (int m = 16; m < 64; m <<= 1) {
            cpsum[ni] += __shfl_xor(cpsum[ni], m);
            cnsum[ni] += __shfl_xor(cnsum[ni], m);
        }
        if (quad == 0) {
            int cc = wn + ni * 16 + l15;
            cP[cc][wid >> 1] = cpsum[ni];
            cN[cc][wid >> 1] = cnsum[ni];
        }
    }
    __syncthreads();
    if (tid < TILE) {
        atomicAdd(&pos_sums[bi * TILE + tid], rP[tid][0] + rP[tid][1]);
        atomicAdd(&neg_sums[bi * TILE + tid], rN[tid][0] + rN[tid][1]);
        if (bi != bj) {
            atomicAdd(&pos_sums[bj * TILE + tid], cP[tid][0] + cP[tid][1]);
            atomicAdd(&neg_sums[bj * TILE + tid], cN[tid][0] + cN[tid][1]);
        }
    }
}

// ------------------------------------------ loss fallback (recompute, r18) ----
__global__ __launch_bounds__(256, 2) void loss_recompute_kernel(
    const short* __restrict__ Lnp, const short* __restrict__ Obp,
    const float* __restrict__ sq, const unsigned* __restrict__ stats,
    float* __restrict__ pos_sums, float* __restrict__ neg_sums) {
    int bi, bj;
    tile_decode(blockIdx.x, bi, bj);
    int tid = threadIdx.x, lane = tid & 63, wid = tid >> 6;
    int wm = (wid >> 1) * 64, wn = (wid & 1) * 64;
    int wm4 = (wid >> 1) * 4, wn4 = (wid & 1) * 4;
    int l15 = lane & 15, quad = lane >> 4;
    int rB = bi * TILE, cB = bj * TILE;

    __shared__ __align__(16) short As[1024 * 8];
    __shared__ __align__(16) short Bs[1024 * 8];
    __shared__ unsigned simW[256 * 33];
    __shared__ float rP[TILE][2], rN[TILE][2];
    __shared__ float cP[TILE][2], cN[TILE][2];
    unsigned* my = &simW[tid * 33];

    f32x4 acc[4][4];

    zero_acc(acc);
    gram_staged<16, 2>(Lnp, bi * 8, bj * 8, As, Bs, tid, wm4, wn4, l15, quad, acc);
    #pragma unroll
    for (int mi = 0; mi < 4; mi++)
        #pragma unroll
        for (int ni = 0; ni < 4; ni++) {
            my[(mi * 4 + ni) * 2 + 0] = pack2(acc[mi][ni][0], acc[mi][ni][1]);
            my[(mi * 4 + ni) * 2 + 1] = pack2(acc[mi][ni][2], acc[mi][ni][3]);
        }

    zero_acc(acc);
    gram_staged<32, 4>(Obp, bi * 8, bj * 8, As, Bs, tid, wm4, wn4, l15, quad, acc);

    float smin = fdec(stats[0]);
    float smax = fdec(stats[1]);
    float d2max = fdec(stats[2]);
    float invr = 1.f / (smax - smin);
    float invem = rsqrtf(d2max);

    float sqj[4];
    #pragma unroll
    for (int ni = 0; ni < 4; ni++) sqj[ni] = sq[cB + wn + ni * 16 + l15];
    float cpsum[4] = {0.f, 0.f, 0.f, 0.f};
    float cnsum[4] = {0.f, 0.f, 0.f, 0.f};

    #pragma unroll
    for (int mi = 0; mi < 4; mi++) {
        f32x4 sqi = *(const f32x4*)&sq[rB + wm + mi * 16 + quad * 4];
        float ps[4] = {0.f, 0.f, 0.f, 0.f};
        float ns[4] = {0.f, 0.f, 0.f, 0.f};
        #pragma unroll
        for (int ni = 0; ni < 4; ni++) {
            f16x2 s01 = ((const f16x2*)my)[(mi * 4 + ni) * 2 + 0];
            f16x2 s23 = ((const f16x2*)my)[(mi * 4 + ni) * 2 + 1];
            #pragma unroll
            for (int r = 0; r < 4; r++) {
                float sraw = (r < 2) ? (float)s01[r] : (float)s23[r - 2];
                float sn = (sraw - smin) * invr;
                float g = acc[mi][ni][r];
                float d2 = fmaxf(sqi[r] + sqj[ni] - 2.f * g, 0.f);
                float eud = (d2 > 0.f) ? sqrtf(d2) * invem : 0.f;
                float dist = eud + sn;
                bool pos = sn > 0.5f;
                float pv = pos ? __expf(dist) : 0.f;
                float nv = pos ? 0.f : __expf(1.0f - dist);
                ps[r] += pv;  ns[r] += nv;
                cpsum[ni] += pv;  cnsum[ni] += nv;
            }
        }
        #pragma unroll
        for (int r = 0; r < 4; r++) {
            #pragma unroll
            for (int m = 1; m < 16; m <<= 1) {
                ps[r] += __shfl_xor(ps[r], m);
                ns[r] += __shfl_xor(ns[r], m);
            }
            if (l15 == 0) {
                int rr = wm + mi * 16 + quad * 4 + r;
                rP[rr][wid & 1] = ps[r];
                rN[rr][wid & 1] = ns[r];
            }
        }
    }
    #pragma unroll
    for (int ni = 0; ni < 4; ni++) {
        #pragma unroll
        for (int m = 16; m < 64; m <<= 1) {
            cpsum[ni] += __shfl_xor(cpsum[ni], m);
            cnsum[ni] += __shfl_xor(cnsum[ni], m);
        }
        if (quad == 0) {
            int cc = wn + ni * 16 + l15;
            cP[cc][wid >> 1] = cpsum[ni];
            cN[cc][wid >> 1] = cnsum[ni];
        }
    }
    __syncthreads();
    if (tid < TILE) {
        atomicAdd(&pos_sums[bi * TILE + tid], rP[tid][0] + rP[tid][1]);
        atomicAdd(&neg_sums[bi * TILE + tid], rN[tid][0] + rN[tid][1]);
        if (bi != bj) {
            atomicAdd(&pos_sums[bj * TILE + tid], cP[tid][0] + cP[tid][1]);
            atomicAdd(&neg_sums[bj * TILE + tid], cN[tid][0] + cN[tid][1]);
        }
    }
}

// ------------------------------------------------------------- finalize ----
__global__ __launch_bounds__(256) void finalize_kernel(
    const float* __restrict__ pos_sums, const float* __restrict__ neg_sums,
    float* __restrict__ out) {
    int t = threadIdx.x;
    float acc = 0.f;
    for (int i = t; i < B_N; i += 256) {
        float p = pos_sums[i], n = neg_sums[i];
        float pl = fmaxf(logf(p), 0.f);
        float nl = (n > 0.f) ? fmaxf(logf(n), 0.f) : 0.f;
        acc += pl + nl;
    }
    #pragma unroll
    for (int m = 1; m < 64; m <<= 1) acc += __shfl_xor(acc, m);
    __shared__ float w4[4];
    if ((t & 63) == 0) w4[t >> 6] = acc;
    __syncthreads();
    if (t == 0) out[0] = (w4[0] + w4[1] + w4[2] + w4[3]) / (float)B_N;
}

// ------------------------------------------------------------------ entry ----
extern "C" void kernel_launch(void* const* d_in, const int* in_sizes, int n_in,
                              void* d_out, int out_size, void* d_ws, size_t ws_size,
                              hipStream_t stream) {
    const float* outputs = (const float*)d_in[0];
    const float* labels  = (const float*)d_in[1];
    float* out = (float*)d_out;
    char* ws = (char*)d_ws;
    __hip_bfloat16* Obp = (__hip_bfloat16*)(ws);
    __hip_bfloat16* Lnp = (__hip_bfloat16*)(ws + 4194304);
    float* sq           = (float*)(ws + 6291456);
    float* pos_sums     = (float*)(ws + 6324224);
    float* neg_sums     = (float*)(ws + 6356992);
    unsigned* stats     = (unsigned*)(ws + 6389760);
    unsigned* simT      = (unsigned*)(ws + 6389824);
    unsigned* eudT      = (unsigned*)(ws + 74547264);
    int big = (ws_size >= WS_NEEDED) ? 1 : 0;

    prep_kernel<<<B_N / 16, 256, 0, stream>>>(outputs, labels, Obp, Lnp, sq,
                                              pos_sums, neg_sums, stats);
    stats_kernel<<<NSUP, 512, 0, stream>>>((const short*)Lnp, (const short*)Obp,
                                           sq, stats, simT, eudT, big);
    if (big)
        loss_stream_kernel<<<NTRI, 256, 0, stream>>>(simT, eudT, stats,
                                                     pos_sums, neg_sums);
    else
        loss_recompute_kernel<<<NTRI, 256, 0, stream>>>((const short*)Lnp,
                                                        (const short*)Obp,
                                                        sq, stats,
                                                        pos_sums, neg_sums);
    finalize_kernel<<<1, 256, 0, stream>>>(pos_sums, neg_sums, out);
}

// Round 6
// 209.575 us; speedup vs baseline: 1.2934x; 1.2934x over previous
//
#include <hip/hip_runtime.h>
#include <hip/hip_bf16.h>

// WeightedLoss round 25: fix r24's race. The tripwire failure was a data
// race from my vmcnt math assuming static VMEM issue order: all args are
// __restrict__, so LLVM may interleave the 16 NT sim-stores with O1's 8
// global_load_lds inside one fence region; r24's loosened VMCNT(24) then
// doesn't retire O1 before its MFMA -> reads un-staged LDS (r23's stricter
// VMCNT(8) was immune; load_lds<->load_lds are mutually ordered intrinsics
// so L-waits were always safe). r25 pins issue order with zero-cost
// asm-memory fences at the two vulnerable boundaries (O1->stores,
// O2->sq-loads) and derives waits {8,8,24,32,8,0} valid under pinning.
// Still the r24 A/B: r19 geometry (2080x256thr, acc[4][4], no spill)
// +counted-vmcnt double-buffer pipeline vs r19's six vmcnt(0) drains.
// Reads: stats 104->60-80us = slice latency was the cost; ~104 unchanged
// = per-block overhead dominates -> restructure passes next round.
// ws: [0] Obp packed 4 MB | [4194304] Lnp packed 2 MB | [6291456] sq
//     [6324224] pos_sums | [6356992] neg_sums | [6389760] stats u32[3]
//     [6389824] simT fp16 2080x16384 (68.2 MB) | [74547264] eudT (68.2 MB)

#define B_N 8192
#define TILE 128
#define NTRI 2080
#define WS_NEEDED 142704704ull

typedef __attribute__((ext_vector_type(8))) short bf16x8;
typedef __attribute__((ext_vector_type(4))) float f32x4;
typedef __attribute__((ext_vector_type(2))) _Float16 f16x2;
typedef __attribute__((ext_vector_type(4))) unsigned u32x4;

typedef const __attribute__((address_space(1))) void g_void;
typedef __attribute__((address_space(3))) void l_void;

__device__ __forceinline__ unsigned fenc(float f) {
    unsigned u = __float_as_uint(f);
    return (u & 0x80000000u) ? ~u : (u | 0x80000000u);
}
__device__ __forceinline__ float fdec(unsigned k) {
    unsigned u = (k & 0x80000000u) ? (k ^ 0x80000000u) : ~k;
    return __uint_as_float(u);
}
__device__ __forceinline__ unsigned pack2(float a, float b) {
    f16x2 p; p[0] = (_Float16)a; p[1] = (_Float16)b;
    return *(unsigned*)&p;
}

// Supertile decode: 4 diagonal 16x16-tri supertiles (136 tiles, b<544),
// then 6 off-diagonal 16x16 supertiles (256 tiles each). bi<=bj always.
__device__ __forceinline__ void tile_decode(int b, int& bi, int& bj) {
    int si, sj, ti, tj;
    if (b < 544) {
        int sb = b / 136, w = b - sb * 136;
        int i = 0;
        while (w >= 16 - i) { w -= 16 - i; i++; }
        si = sb; sj = sb; ti = i; tj = i + w;
    } else {
        int q = (b - 544) >> 8, w = (b - 544) & 255;
        int i = 0;
        while (q >= 3 - i) { q -= 3 - i; i++; }
        si = i; sj = i + 1 + q;
        ti = w >> 4; tj = w & 15;
    }
    bi = si * 16 + ti; bj = sj * 16 + tj;
}

// ---------------------------------------------------------------- prep ----
__global__ __launch_bounds__(256) void prep_kernel(
    const float* __restrict__ outputs, const float* __restrict__ labels,
    __hip_bfloat16* __restrict__ Obp, __hip_bfloat16* __restrict__ Lnp,
    float* __restrict__ sq, float* __restrict__ pos_sums,
    float* __restrict__ neg_sums, unsigned* __restrict__ stats) {
    int g = blockIdx.x, tid = threadIdx.x;
    int rl = tid >> 4, c = tid & 15;
    int row = g * 16 + rl;
    __shared__ __align__(16) short tO[16][264];
    __shared__ __align__(16) short tL[16][136];

    float s = 0.f;
    #pragma unroll
    for (int k = 0; k < 4; k++) {
        f32x4 v = *(const f32x4*)&outputs[(size_t)row * 256 + c * 16 + k * 4];
        s += v[0]*v[0] + v[1]*v[1] + v[2]*v[2] + v[3]*v[3];
        __hip_bfloat16 b4[4];
        #pragma unroll
        for (int i = 0; i < 4; i++) b4[i] = __float2bfloat16(v[i]);
        *(uint2*)&tO[rl][c * 16 + k * 4] = *(uint2*)b4;
    }
    #pragma unroll
    for (int m = 1; m < 16; m <<= 1) s += __shfl_xor(s, m);
    if (c == 0) sq[row] = s;

    float ls = 0.f;
    f32x4 u0 = *(const f32x4*)&labels[(size_t)row * 128 + c * 8];
    f32x4 u1 = *(const f32x4*)&labels[(size_t)row * 128 + c * 8 + 4];
    ls += u0[0]*u0[0] + u0[1]*u0[1] + u0[2]*u0[2] + u0[3]*u0[3];
    ls += u1[0]*u1[0] + u1[1]*u1[1] + u1[2]*u1[2] + u1[3]*u1[3];
    #pragma unroll
    for (int m = 1; m < 16; m <<= 1) ls += __shfl_xor(ls, m);
    float inv = 1.f / (sqrtf(ls) + 1e-12f);
    {
        __hip_bfloat16 b4[4];
        #pragma unroll
        for (int i = 0; i < 4; i++) b4[i] = __float2bfloat16(u0[i] * inv);
        *(uint2*)&tL[rl][c * 8] = *(uint2*)b4;
        #pragma unroll
        for (int i = 0; i < 4; i++) b4[i] = __float2bfloat16(u1[i] * inv);
        *(uint2*)&tL[rl][c * 8 + 4] = *(uint2*)b4;
    }
    if (tid < 16) { pos_sums[g * 16 + tid] = 0.f; neg_sums[g * 16 + tid] = 0.f; }
    if (g == 0 && tid == 0) {
        stats[0] = 0xFFFFFFFFu; stats[1] = 0u; stats[2] = 0u;
    }
    __syncthreads();

    #pragma unroll
    for (int q = 0; q < 2; q++) {
        int sl = tid * 2 + q;
        int o = sl >> 4, rr = sl & 15;
        uint4 d = *(uint4*)&tO[rr][o * 8];
        *(uint4*)&Obp[(size_t)g * 4096 + (size_t)sl * 8] = d;
    }
    {
        int o = tid >> 4, rr = tid & 15;
        uint4 d = *(uint4*)&tL[rr][o * 8];
        *(uint4*)&Lnp[(size_t)g * 2048 + (size_t)tid * 8] = d;
    }
}

// ------------------------------------------------- staged slice gram ----
template<int KD8>
__device__ __forceinline__ void stage_slice(
    const short* __restrict__ P, int g0, int o0, short* L, int tid) {
    #pragma unroll
    for (int p = 0; p < 4; p++) {
        int u = p * 256 + tid;
        int gl = u >> 7, off = u & 127;
        size_t gu = ((size_t)(g0 + gl) * KD8 + o0) * 16 + off;
        __builtin_amdgcn_global_load_lds((g_void*)(P + gu * 8),
                                         (l_void*)(L + (size_t)u * 8), 16, 0, 0);
    }
}

__device__ __forceinline__ void mfma_slice(
    const short* As, const short* Bs, int wm4, int wn4,
    int l15, int quad, f32x4 (&acc)[4][4]) {
    #pragma unroll
    for (int kc = 0; kc < 2; kc++) {
        bf16x8 a[4], b[4];
        #pragma unroll
        for (int mi = 0; mi < 4; mi++)
            a[mi] = *(const bf16x8*)&As[((wm4 + mi) * 128
                                         + (kc * 4 + quad) * 16 + l15) * 8];
        #pragma unroll
        for (int ni = 0; ni < 4; ni++)
            b[ni] = *(const bf16x8*)&Bs[((wn4 + ni) * 128
                                         + (kc * 4 + quad) * 16 + l15) * 8];
        #pragma unroll
        for (int mi = 0; mi < 4; mi++)
            #pragma unroll
            for (int ni = 0; ni < 4; ni++)
                acc[mi][ni] = __builtin_amdgcn_mfma_f32_16x16x32_bf16(
                    a[mi], b[ni], acc[mi][ni], 0, 0, 0);
    }
}

__device__ __forceinline__ void zero_acc(f32x4 (&acc)[4][4]) {
    #pragma unroll
    for (int mi = 0; mi < 4; mi++)
        #pragma unroll
        for (int ni = 0; ni < 4; ni++) {
            f32x4 z = {0.f, 0.f, 0.f, 0.f};
            acc[mi][ni] = z;
        }
}

// (serial-staged gram kept for the loss_recompute fallback)
template<int KD8, int NS>
__device__ __forceinline__ void gram_staged(
    const short* __restrict__ P, int gA0, int gB0,
    short* As, short* Bs, int tid, int wm4, int wn4,
    int l15, int quad, f32x4 (&acc)[4][4]) {
    #pragma unroll
    for (int s = 0; s < NS; s++) {
        __syncthreads();
        stage_slice<KD8>(P, gA0, s * 8, As, tid);
        stage_slice<KD8>(P, gB0, s * 8, Bs, tid);
        __syncthreads();
        mfma_slice(As, Bs, wm4, wn4, l15, quad, acc);
    }
}

#define VMCNT(n) asm volatile("s_waitcnt vmcnt(" #n ")" ::: "memory")
#define BAR() __builtin_amdgcn_s_barrier()
#define FENCE() asm volatile("" ::: "memory")

// ---------------------------------------------------------------- stats ----
// r19 geometry (128^2 tile, 4 waves) + counted-vmcnt double-buffer pipeline.
// Issue order PINNED by compiler fences (asm memory clobbers) so the waits
// are valid under any legal schedule:
//   L0(8) | L1(8) |w8| O0(8) |w8| O1(8) F ST(16) |w24| O2(8) F SQ(8)
//   |w32| O3(8) |w8| ... |w0|
// Each wN retires exactly the load_lds group the next MFMA needs.
__global__ __launch_bounds__(256, 2) void stats_kernel(
    const short* __restrict__ Lnp, const short* __restrict__ Obp,
    const float* __restrict__ sq, unsigned* __restrict__ stats,
    unsigned* __restrict__ simT, unsigned* __restrict__ eudT, int store) {
    int bi, bj;
    tile_decode(blockIdx.x, bi, bj);
    int tid = threadIdx.x, lane = tid & 63, wid = tid >> 6;
    int wm = (wid >> 1) * 64, wn = (wid & 1) * 64;
    int wm4 = (wid >> 1) * 4, wn4 = (wid & 1) * 4;
    int l15 = lane & 15, quad = lane >> 4;
    int rB = bi * TILE, cB = bj * TILE;
    size_t tB = (size_t)blockIdx.x * 8192 + (size_t)tid * 4;

    __shared__ __align__(16) short As[2][8192];
    __shared__ __align__(16) short Bs[2][8192];
    __shared__ float red[3][4];

    float lmin = 1e30f, lmax = -1e30f, dmax = 0.f;
    f32x4 acc[4][4];

    // ---- labels gram: L0, L1 ----
    zero_acc(acc);
    stage_slice<16>(Lnp, bi * 8, 0, As[0], tid);   // L0   [8]
    stage_slice<16>(Lnp, bj * 8, 0, Bs[0], tid);
    stage_slice<16>(Lnp, bi * 8, 8, As[1], tid);   // L1   [16]
    stage_slice<16>(Lnp, bj * 8, 8, Bs[1], tid);
    VMCNT(8); BAR();                                // L0 ready (L1 younger)
    mfma_slice(As[0], Bs[0], wm4, wn4, l15, quad, acc);
    BAR();                                          // buf0 readers done
    stage_slice<32>(Obp, bi * 8, 0, As[0], tid);   // O0   [L1:8 + O0:8]
    stage_slice<32>(Obp, bj * 8, 0, Bs[0], tid);
    VMCNT(8); BAR();                                // L1 ready (O0 younger)
    mfma_slice(As[1], Bs[1], wm4, wn4, l15, quad, acc);
    BAR();                                          // buf1 readers done
    stage_slice<32>(Obp, bi * 8, 8, As[1], tid);   // O1   [O0:8 + O1:8]
    stage_slice<32>(Obp, bj * 8, 8, Bs[1], tid);
    FENCE();                                        // pin: O1 before ST

    // ---- sim epilogue: pack + min/max + NT stores (fills O0/O1 latency) ----
    #pragma unroll
    for (int mi = 0; mi < 4; mi++) {
        u32x4 v0, v1;
        #pragma unroll
        for (int ni = 0; ni < 4; ni++)
            #pragma unroll
            for (int h = 0; h < 2; h++) {
                float s0 = acc[mi][ni][2 * h], s1 = acc[mi][ni][2 * h + 1];
                lmin = fminf(lmin, fminf(s0, s1));
                lmax = fmaxf(lmax, fmaxf(s0, s1));
                int j = ni * 2 + h;
                unsigned pk = pack2(s0, s1);
                if (j < 4) v0[j] = pk; else v1[j - 4] = pk;
            }
        if (store) {
            __builtin_nontemporal_store(v0, (u32x4*)(simT + tB + (mi * 2 + 0) * 1024));
            __builtin_nontemporal_store(v1, (u32x4*)(simT + tB + (mi * 2 + 1) * 1024));
        }
    }                                               // [O0:8 + O1:8 + ST:16]

    // ---- outputs gram: O0..O3 pipelined ----
    zero_acc(acc);
    VMCNT(24); BAR();                               // retire 8 oldest = O0
    mfma_slice(As[0], Bs[0], wm4, wn4, l15, quad, acc);
    BAR();                                          // buf0 free
    stage_slice<32>(Obp, bi * 8, 16, As[0], tid);  // O2   [O1 ST O2]
    stage_slice<32>(Obp, bj * 8, 16, Bs[0], tid);
    FENCE();                                        // pin: O2 before SQ
    // sq prefetch (8 VMEM; compiler manages their register waits)
    float sqj[4]; f32x4 sqi4[4];
    #pragma unroll
    for (int ni = 0; ni < 4; ni++) sqj[ni] = sq[cB + wn + ni * 16 + l15];
    #pragma unroll
    for (int mi = 0; mi < 4; mi++)
        sqi4[mi] = *(const f32x4*)&sq[rB + wm + mi * 16 + quad * 4];
    VMCNT(32); BAR();                               // 40 out, retire 8 = O1
    mfma_slice(As[1], Bs[1], wm4, wn4, l15, quad, acc);
    BAR();                                          // buf1 free
    stage_slice<32>(Obp, bi * 8, 24, As[1], tid);  // O3   [ST O2 SQ O3]
    stage_slice<32>(Obp, bj * 8, 24, Bs[1], tid);
    VMCNT(8); BAR();                                // 40 out, retire 32 =
    mfma_slice(As[0], Bs[0], wm4, wn4, l15, quad, acc);  // ST+O2+SQ -> O2 ok
    VMCNT(0); BAR();                                // O3 ready
    mfma_slice(As[1], Bs[1], wm4, wn4, l15, quad, acc);

    // ---- eud epilogue ----
    #pragma unroll
    for (int mi = 0; mi < 4; mi++) {
        f32x4 sqi = sqi4[mi];
        u32x4 v0, v1;
        #pragma unroll
        for (int ni = 0; ni < 4; ni++)
            #pragma unroll
            for (int h = 0; h < 2; h++) {
                float d20 = fmaxf(sqi[2*h]   + sqj[ni] - 2.f * acc[mi][ni][2*h],   0.f);
                float d21 = fmaxf(sqi[2*h+1] + sqj[ni] - 2.f * acc[mi][ni][2*h+1], 0.f);
                dmax = fmaxf(dmax, fmaxf(d20, d21));
                float e0 = (d20 > 0.f) ? sqrtf(d20) : 0.f;
                float e1 = (d21 > 0.f) ? sqrtf(d21) : 0.f;
                int j = ni * 2 + h;
                unsigned pk = pack2(e0, e1);
                if (j < 4) v0[j] = pk; else v1[j - 4] = pk;
            }
        if (store) {
            __builtin_nontemporal_store(v0, (u32x4*)(eudT + tB + (mi * 2 + 0) * 1024));
            __builtin_nontemporal_store(v1, (u32x4*)(eudT + tB + (mi * 2 + 1) * 1024));
        }
    }

    // ---- reductions ----
    #pragma unroll
    for (int m = 1; m < 64; m <<= 1) {
        lmin = fminf(lmin, __shfl_xor(lmin, m));
        lmax = fmaxf(lmax, __shfl_xor(lmax, m));
        dmax = fmaxf(dmax, __shfl_xor(dmax, m));
    }
    if ((tid & 63) == 0) { red[0][wid] = lmin; red[1][wid] = lmax; red[2][wid] = dmax; }
    __syncthreads();
    if (tid == 0) {
        lmin = fminf(fminf(red[0][0], red[0][1]), fminf(red[0][2], red[0][3]));
        lmax = fmaxf(fmaxf(red[1][0], red[1][1]), fmaxf(red[1][2], red[1][3]));
        dmax = fmaxf(fmaxf(red[2][0], red[2][1]), fmaxf(red[2][2], red[2][3]));
        atomicMin(&stats[0], fenc(lmin));
        atomicMax(&stats[1], fenc(lmax));
        atomicMax(&stats[2], fenc(dmax));
    }
}

// ----------------------------------------------------------- loss stream ----
// Pure streaming epilogue (r7-verified): coalesced NT dwordx4 reads,
// exp terms, row+col sums, one atomic per row per block.
__global__ __launch_bounds__(256) void loss_stream_kernel(
    const unsigned* __restrict__ simT, const unsigned* __restrict__ eudT,
    const unsigned* __restrict__ stats,
    float* __restrict__ pos_sums, float* __restrict__ neg_sums) {
    int bi, bj;
    tile_decode(blockIdx.x, bi, bj);
    int tid = threadIdx.x, lane = tid & 63, wid = tid >> 6;
    int wm = (wid >> 1) * 64, wn = (wid & 1) * 64;
    int l15 = lane & 15, quad = lane >> 4;
    size_t tB = (size_t)blockIdx.x * 8192 + (size_t)tid * 4;

    float smin = fdec(stats[0]);
    float smax = fdec(stats[1]);
    float d2max = fdec(stats[2]);
    float invr = 1.f / (smax - smin);
    float invem = rsqrtf(d2max);

    __shared__ float rP[TILE][2], rN[TILE][2];
    __shared__ float cP[TILE][2], cN[TILE][2];
    float cpsum[4] = {0.f, 0.f, 0.f, 0.f};
    float cnsum[4] = {0.f, 0.f, 0.f, 0.f};

    #pragma unroll
    for (int mi = 0; mi < 4; mi++) {
        u32x4 s0 = __builtin_nontemporal_load((const u32x4*)(simT + tB + (mi * 2 + 0) * 1024));
        u32x4 s1 = __builtin_nontemporal_load((const u32x4*)(simT + tB + (mi * 2 + 1) * 1024));
        u32x4 e0 = __builtin_nontemporal_load((const u32x4*)(eudT + tB + (mi * 2 + 0) * 1024));
        u32x4 e1 = __builtin_nontemporal_load((const u32x4*)(eudT + tB + (mi * 2 + 1) * 1024));
        float ps[4] = {0.f, 0.f, 0.f, 0.f};
        float ns[4] = {0.f, 0.f, 0.f, 0.f};
        #pragma unroll
        for (int j = 0; j < 8; j++) {
            unsigned sv = (j < 4) ? s0[j] : s1[j - 4];
            unsigned ev = (j < 4) ? e0[j] : e1[j - 4];
            int ni = j >> 1, h = j & 1;
            f16x2 spair = *(f16x2*)&sv;
            f16x2 epair = *(f16x2*)&ev;
            #pragma unroll
            for (int e = 0; e < 2; e++) {
                float sn = ((float)spair[e] - smin) * invr;
                float dist = (float)epair[e] * invem + sn;
                bool pos = sn > 0.5f;   // TAU
                float pv = pos ? __expf(dist) : 0.f;
                float nv = pos ? 0.f : __expf(1.0f - dist);  // MAG = 1
                ps[2 * h + e] += pv;  ns[2 * h + e] += nv;
                cpsum[ni] += pv;  cnsum[ni] += nv;
            }
        }
        #pragma unroll
        for (int r = 0; r < 4; r++) {
            #pragma unroll
            for (int m = 1; m < 16; m <<= 1) {
                ps[r] += __shfl_xor(ps[r], m);
                ns[r] += __shfl_xor(ns[r], m);
            }
            if (l15 == 0) {
                int rr = wm + mi * 16 + quad * 4 + r;
                rP[rr][wid & 1] = ps[r];
                rN[rr][wid & 1] = ns[r];
            }
        }
    }
    #pragma unroll
    for (int ni = 0; ni < 4; ni++) {
        #pragma unroll
        for (int m = 16; m < 64; m <<= 1) {
            cpsum[ni] += __shfl_xor(cpsum[ni], m);
            cnsum[ni] += __shfl_xor(cnsum[ni], m);
        }
        if (quad == 0) {
            int cc = wn + ni * 16 + l15;
            cP[cc][wid >> 1] = cpsum[ni];
            cN[cc][wid >> 1] = cnsum[ni];
        }
    }
    __syncthreads();
    if (tid < TILE) {
        atomicAdd(&pos_sums[bi * TILE + tid], rP[tid][0] + rP[tid][1]);
        atomicAdd(&neg_sums[bi * TILE + tid], rN[tid][0] + rN[tid][1]);
        if (bi != bj) {
            atomicAdd(&pos_sums[bj * TILE + tid], cP[tid][0] + cP[tid][1]);
            atomicAdd(&neg_sums[bj * TILE + tid], cN[tid][0] + cN[tid][1]);
        }
    }
}

// ------------------------------------------ loss fallback (recompute, r18) ----
__global__ __launch_bounds__(256, 2) void loss_recompute_kernel(
    const short* __restrict__ Lnp, const short* __restrict__ Obp,
    const float* __restrict__ sq, const unsigned* __restrict__ stats,
    float* __restrict__ pos_sums, float* __restrict__ neg_sums) {
    int bi, bj;
    tile_decode(blockIdx.x, bi, bj);
    int tid = threadIdx.x, lane = tid & 63, wid = tid >> 6;
    int wm = (wid >> 1) * 64, wn = (wid & 1) * 64;
    int wm4 = (wid >> 1) * 4, wn4 = (wid & 1) * 4;
    int l15 = lane & 15, quad = lane >> 4;
    int rB = bi * TILE, cB = bj * TILE;

    __shared__ __align__(16) short As[1024 * 8];
    __shared__ __align__(16) short Bs[1024 * 8];
    __shared__ unsigned simW[256 * 33];
    __shared__ float rP[TILE][2], rN[TILE][2];
    __shared__ float cP[TILE][2], cN[TILE][2];
    unsigned* my = &simW[tid * 33];

    f32x4 acc[4][4];

    zero_acc(acc);
    gram_staged<16, 2>(Lnp, bi * 8, bj * 8, As, Bs, tid, wm4, wn4, l15, quad, acc);
    #pragma unroll
    for (int mi = 0; mi < 4; mi++)
        #pragma unroll
        for (int ni = 0; ni < 4; ni++) {
            my[(mi * 4 + ni) * 2 + 0] = pack2(acc[mi][ni][0], acc[mi][ni][1]);
            my[(mi * 4 + ni) * 2 + 1] = pack2(acc[mi][ni][2], acc[mi][ni][3]);
        }

    zero_acc(acc);
    gram_staged<32, 4>(Obp, bi * 8, bj * 8, As, Bs, tid, wm4, wn4, l15, quad, acc);

    float smin = fdec(stats[0]);
    float smax = fdec(stats[1]);
    float d2max = fdec(stats[2]);
    float invr = 1.f / (smax - smin);
    float invem = rsqrtf(d2max);

    float sqj[4];
    #pragma unroll
    for (int ni = 0; ni < 4; ni++) sqj[ni] = sq[cB + wn + ni * 16 + l15];
    float cpsum[4] = {0.f, 0.f, 0.f, 0.f};
    float cnsum[4] = {0.f, 0.f, 0.f, 0.f};

    #pragma unroll
    for (int mi = 0; mi < 4; mi++) {
        f32x4 sqi = *(const f32x4*)&sq[rB + wm + mi * 16 + quad * 4];
        float ps[4] = {0.f, 0.f, 0.f, 0.f};
        float ns[4] = {0.f, 0.f, 0.f, 0.f};
        #pragma unroll
        for (int ni = 0; ni < 4; ni++) {
            f16x2 s01 = ((const f16x2*)my)[(mi * 4 + ni) * 2 + 0];
            f16x2 s23 = ((const f16x2*)my)[(mi * 4 + ni) * 2 + 1];
            #pragma unroll
            for (int r = 0; r < 4; r++) {
                float sraw = (r < 2) ? (float)s01[r] : (float)s23[r - 2];
                float sn = (sraw - smin) * invr;
                float g = acc[mi][ni][r];
                float d2 = fmaxf(sqi[r] + sqj[ni] - 2.f * g, 0.f);
                float eud = (d2 > 0.f) ? sqrtf(d2) * invem : 0.f;
                float dist = eud + sn;
                bool pos = sn > 0.5f;
                float pv = pos ? __expf(dist) : 0.f;
                float nv = pos ? 0.f : __expf(1.0f - dist);
                ps[r] += pv;  ns[r] += nv;
                cpsum[ni] += pv;  cnsum[ni] += nv;
            }
        }
        #pragma unroll
        for (int r = 0; r < 4; r++) {
            #pragma unroll
            for (int m = 1; m < 16; m <<= 1) {
                ps[r] += __shfl_xor(ps[r], m);
                ns[r] += __shfl_xor(ns[r], m);
            }
            if (l15 == 0) {
                int rr = wm + mi * 16 + quad * 4 + r;
                rP[rr][wid & 1] = ps[r];
                rN[rr][wid & 1] = ns[r];
            }
        }
    }
    #pragma unroll
    for (int ni = 0; ni < 4; ni++) {
        #pragma unroll
        for (int m = 16; m < 64; m <<= 1) {
            cpsum[ni] += __shfl_xor(cpsum[ni], m);
            cnsum[ni] += __shfl_xor(cnsum[ni], m);
        }
        if (quad == 0) {
            int cc = wn + ni * 16 + l15;
            cP[cc][wid >> 1] = cpsum[ni];
            cN[cc][wid >> 1] = cnsum[ni];
        }
    }
    __syncthreads();
    if (tid < TILE) {
        atomicAdd(&pos_sums[bi * TILE + tid], rP[tid][0] + rP[tid][1]);
        atomicAdd(&neg_sums[bi * TILE + tid], rN[tid][0] + rN[tid][1]);
        if (bi != bj) {
            atomicAdd(&pos_sums[bj * TILE + tid], cP[tid][0] + cP[tid][1]);
            atomicAdd(&neg_sums[bj * TILE + tid], cN[tid][0] + cN[tid][1]);
        }
    }
}

// ------------------------------------------------------------- finalize ----
__global__ __launch_bounds__(256) void finalize_kernel(
    const float* __restrict__ pos_sums, const float* __restrict__ neg_sums,
    float* __restrict__ out) {
    int t = threadIdx.x;
    float acc = 0.f;
    for (int i = t; i < B_N; i += 256) {
        float p = pos_sums[i], n = neg_sums[i];
        float pl = fmaxf(logf(p), 0.f);
        float nl = (n > 0.f) ? fmaxf(logf(n), 0.f) : 0.f;
        acc += pl + nl;
    }
    #pragma unroll
    for (int m = 1; m < 64; m <<= 1) acc += __shfl_xor(acc, m);
    __shared__ float w4[4];
    if ((t & 63) == 0) w4[t >> 6] = acc;
    __syncthreads();
    if (t == 0) out[0] = (w4[0] + w4[1] + w4[2] + w4[3]) / (float)B_N;
}

// ------------------------------------------------------------------ entry ----
extern "C" void kernel_launch(void* const* d_in, const int* in_sizes, int n_in,
                              void* d_out, int out_size, void* d_ws, size_t ws_size,
                              hipStream_t stream) {
    const float* outputs = (const float*)d_in[0];
    const float* labels  = (const float*)d_in[1];
    float* out = (float*)d_out;
    char* ws = (char*)d_ws;
    __hip_bfloat16* Obp = (__hip_bfloat16*)(ws);
    __hip_bfloat16* Lnp = (__hip_bfloat16*)(ws + 4194304);
    float* sq           = (float*)(ws + 6291456);
    float* pos_sums     = (float*)(ws + 6324224);
    float* neg_sums     = (float*)(ws + 6356992);
    unsigned* stats     = (unsigned*)(ws + 6389760);
    unsigned* simT      = (unsigned*)(ws + 6389824);
    unsigned* eudT      = (unsigned*)(ws + 74547264);
    int big = (ws_size >= WS_NEEDED) ? 1 : 0;

    prep_kernel<<<B_N / 16, 256, 0, stream>>>(outputs, labels, Obp, Lnp, sq,
                                              pos_sums, neg_sums, stats);
    stats_kernel<<<NTRI, 256, 0, stream>>>((const short*)Lnp, (const short*)Obp,
                                           sq, stats, simT, eudT, big);
    if (big)
        loss_stream_kernel<<<NTRI, 256, 0, stream>>>(simT, eudT, stats,
                                                     pos_sums, neg_sums);
    else
        loss_recompute_kernel<<<NTRI, 256, 0, stream>>>((const short*)Lnp,
                                                        (const short*)Obp,
                                                        sq, stats,
                                                        pos_sums, neg_sums);
    finalize_kernel<<<1, 256, 0, stream>>>(pos_sums, neg_sums, out);
}